// Round 2
// baseline (575.860 us; speedup 1.0000x reference)
//
#include <hip/hip_runtime.h>
#include <hip/hip_bf16.h>

#define N_NODES 4096
#define CIN     128
#define COUT    256
#define WIDTH   64
#define KDIM    16
#define SLOPE   0.1f
#define WSLOPE  0.2f
#define BN_EPS  1e-5f

__device__ __forceinline__ float lrelu(float x, float s) { return x > 0.f ? x : s * x; }

// Load a "float input" element: the harness may store float32 (per reference)
// or bf16 (dataset conversion). `isf32` is a runtime-uniform flag.
__device__ __forceinline__ float ldf(const void* p, size_t i, int isf32) {
  return isf32 ? ((const float*)p)[i]
               : __bfloat162float(((const __hip_bfloat16*)p)[i]);
}

// ---- dtype sniff: reinterpret x as bf16; f32 data shows huge/NaN values ----
__global__ void sniff_kernel(const void* x, int* flag) {
  int t = threadIdx.x;
  const __hip_bfloat16* p = (const __hip_bfloat16*)x;
  int bad = 0;
  for (int i = t; i < 256; i += 64) {
    float v = __bfloat162float(p[i]);
    if (!(fabsf(v) < 1e4f)) bad = 1;   // catches huge and NaN
  }
  unsigned long long m = __ballot(bad);
  if (t == 0) *flag = (m != 0ull) ? 1 : 0;   // 1 => underlying data is f32
}

// ---------------- column mean / biased var over M rows (input array) --------
__global__ __launch_bounds__(256) void col_stats_in_kernel(
    const void* __restrict__ X, int M, int C, const int* __restrict__ flagp,
    float* __restrict__ mean, float* __restrict__ var) {
  int isf = *flagp;
  int c = blockIdx.x;
  int t = threadIdx.x;
  float s = 0.f, sq = 0.f;
  for (int r = t; r < M; r += 256) {
    float v = ldf(X, (size_t)r * C + c, isf);
    s += v; sq += v * v;
  }
  __shared__ float ls[256], lq[256];
  ls[t] = s; lq[t] = sq; __syncthreads();
  for (int st = 128; st > 0; st >>= 1) {
    if (t < st) { ls[t] += ls[t + st]; lq[t] += lq[t + st]; }
    __syncthreads();
  }
  if (t == 0) {
    float m = ls[0] / M;
    mean[c] = m;
    var[c] = lq[0] / M - m * m;
  }
}

// ---------------- same but over a f32 workspace array ----------------
__global__ __launch_bounds__(256) void col_stats_f32_kernel(
    const float* __restrict__ X, int M, int C,
    float* __restrict__ mean, float* __restrict__ var) {
  int c = blockIdx.x;
  int t = threadIdx.x;
  float s = 0.f, sq = 0.f;
  for (int r = t; r < M; r += 256) {
    float v = X[(size_t)r * C + c];
    s += v; sq += v * v;
  }
  __shared__ float ls[256], lq[256];
  ls[t] = s; lq[t] = sq; __syncthreads();
  for (int st = 128; st > 0; st >>= 1) {
    if (t < st) { ls[t] += ls[t + st]; lq[t] += lq[t + st]; }
    __syncthreads();
  }
  if (t == 0) {
    float m = ls[0] / M;
    mean[c] = m;
    var[c] = lq[0] / M - m * m;
  }
}

// -------- A = lrelu(bn_id(x)), B = lrelu(bn_in(x)) (shared x stats) --------
__global__ __launch_bounds__(256) void act_ab_kernel(
    const void* __restrict__ x, const int* __restrict__ flagp,
    const float* __restrict__ mean, const float* __restrict__ var,
    const void* __restrict__ gA, const void* __restrict__ bA,
    const void* __restrict__ gB, const void* __restrict__ bB,
    float* __restrict__ A, float* __restrict__ B) {
  int isf = *flagp;
  int idx = blockIdx.x * 256 + threadIdx.x;      // over N*CIN
  int c = idx & (CIN - 1);
  float xn = (ldf(x, idx, isf) - mean[c]) * rsqrtf(var[c] + BN_EPS);
  A[idx] = lrelu(xn * ldf(gA, c, isf) + ldf(bA, c, isf), SLOPE);
  B[idx] = lrelu(xn * ldf(gB, c, isf) + ldf(bB, c, isf), SLOPE);
}

// -------- C[M,Nd] = A[M,Kd] (f32 ws) @ W[Kd,Nd] (input); wave per row --------
__global__ __launch_bounds__(256) void gemm_act_kernel(
    const float* __restrict__ A, const void* __restrict__ W,
    const int* __restrict__ flagp, float* __restrict__ C, int Kd, int Nd) {
  int isf = *flagp;
  int lane = threadIdx.x & 63;
  int wv = threadIdx.x >> 6;
  int j = blockIdx.x * 64 + lane;
  int i = blockIdx.y * 4 + wv;
  const float* Ar = A + (size_t)i * Kd;
  float s = 0.f;
  for (int k = 0; k < Kd; k += 4) {
    float4 a = *(const float4*)(Ar + k);
    s += a.x * ldf(W, (size_t)(k + 0) * Nd + j, isf);
    s += a.y * ldf(W, (size_t)(k + 1) * Nd + j, isf);
    s += a.z * ldf(W, (size_t)(k + 2) * Nd + j, isf);
    s += a.w * ldf(W, (size_t)(k + 3) * Nd + j, isf);
  }
  C[(size_t)i * Nd + j] = s;
}

// -------- Y = lrelu(bn(X)) elementwise on ws f32, C channels pow2 --------
__global__ __launch_bounds__(256) void bnleaky_kernel(
    const float* __restrict__ X, const float* __restrict__ mean,
    const float* __restrict__ var,
    const void* __restrict__ g, const void* __restrict__ b,
    const int* __restrict__ flagp, float* __restrict__ Y, int Cmask) {
  int isf = *flagp;
  int idx = blockIdx.x * 256 + threadIdx.x;
  int c = idx & Cmask;
  float xn = (X[idx] - mean[c]) * rsqrtf(var[c] + BN_EPS);
  Y[idx] = lrelu(xn * ldf(g, c, isf) + ldf(b, c, isf), SLOPE);
}

// -------- input -> f32 convert --------
__global__ __launch_bounds__(256) void cvt_kernel(
    const void* __restrict__ src, const int* __restrict__ flagp,
    float* __restrict__ dst, int n) {
  int isf = *flagp;
  int i = blockIdx.x * 256 + threadIdx.x;
  if (i < n) dst[i] = ldf(src, i, isf);
}

// -------- per-edge gate weights w[E,16] --------
__global__ __launch_bounds__(256) void edge_w_kernel(
    const int* __restrict__ src, const int* __restrict__ dst,
    const void* __restrict__ pos, const void* __restrict__ ori,
    const int* __restrict__ seq,
    const void* __restrict__ Ws, const void* __restrict__ bs,
    const int* __restrict__ flagp,
    float* __restrict__ wbuf, int E, float inv_r, int hl) {
  int isf = *flagp;
  int e = blockIdx.x * 256 + threadIdx.x;
  if (e >= E) return;
  int j = src[e], i = dst[e];
  float px = ldf(pos, j * 3 + 0, isf) - ldf(pos, i * 3 + 0, isf);
  float py = ldf(pos, j * 3 + 1, isf) - ldf(pos, i * 3 + 1, isf);
  float pz = ldf(pos, j * 3 + 2, isf) - ldf(pos, i * 3 + 2, isf);
  float dist = sqrtf(px * px + py * py + pz * pz);
  float inv = 1.0f / (dist + 1e-9f);
  float dx = px * inv, dy = py * inv, dz = pz * inv;
  float fi[9], fj[9];
#pragma unroll
  for (int t = 0; t < 9; t++) {
    fi[t] = ldf(ori, (size_t)i * 9 + t, isf);
    fj[t] = ldf(ori, (size_t)j * 9 + t, isf);
  }
  float feat[7];
  feat[0] = dist * inv_r;
  feat[1] = fi[0] * dx + fi[1] * dy + fi[2] * dz;
  feat[2] = fi[3] * dx + fi[4] * dy + fi[5] * dz;
  feat[3] = fi[6] * dx + fi[7] * dy + fi[8] * dz;
  feat[4] = fi[0] * fj[0] + fi[1] * fj[1] + fi[2] * fj[2];
  feat[5] = fi[3] * fj[3] + fi[4] * fj[4] + fi[5] * fj[5];
  feat[6] = fi[6] * fj[6] + fi[7] * fj[7] + fi[8] * fj[8];
  int d = seq[j] - seq[i];
  d = d < -hl ? -hl : (d > hl ? hl : d);
  int bin = d + hl;
  const size_t Wo = (size_t)bin * 7 * KDIM;
  const size_t bo = (size_t)bin * KDIM;
#pragma unroll
  for (int k = 0; k < KDIM; k++) {
    float a = ldf(bs, bo + k, isf);
#pragma unroll
    for (int c = 0; c < 7; c++) a += feat[c] * ldf(Ws, Wo + c * KDIM + k, isf);
    wbuf[(size_t)e * KDIM + k] = lrelu(a, WSLOPE);
  }
}

// -------- per-node aggregation + branch GEMM (dst sorted ascending) --------
template <int O>
__global__ __launch_bounds__(256) void agg_kernel(
    const int* __restrict__ src, const int* __restrict__ dst, int E,
    const float* __restrict__ h, const float* __restrict__ wbuf,
    const float* __restrict__ Wf, float* __restrict__ cat, int coloff) {
  int lane = threadIdx.x & 63;
  int n = blockIdx.x * 4 + (threadIdx.x >> 6);   // wave per node

  int lo = 0, hi = E;
  while (lo < hi) { int mid = (lo + hi) >> 1; if (dst[mid] < n) lo = mid + 1; else hi = mid; }
  int start = lo;
  hi = E;
  while (lo < hi) { int mid = (lo + hi) >> 1; if (dst[mid] < n + 1) lo = mid + 1; else hi = mid; }
  int end = lo;

  float acc[KDIM];
#pragma unroll
  for (int k = 0; k < KDIM; k++) acc[k] = 0.f;

  for (int e = start; e < end; e++) {
    int j = src[e];
    float hj = h[(size_t)j * WIDTH + lane];
    const float4* wv = (const float4*)(wbuf + (size_t)e * KDIM);
    float4 w0 = wv[0], w1 = wv[1], w2 = wv[2], w3 = wv[3];
    acc[0]  += w0.x * hj; acc[1]  += w0.y * hj; acc[2]  += w0.z * hj; acc[3]  += w0.w * hj;
    acc[4]  += w1.x * hj; acc[5]  += w1.y * hj; acc[6]  += w1.z * hj; acc[7]  += w1.w * hj;
    acc[8]  += w2.x * hj; acc[9]  += w2.y * hj; acc[10] += w2.z * hj; acc[11] += w2.w * hj;
    acc[12] += w3.x * hj; acc[13] += w3.y * hj; acc[14] += w3.z * hj; acc[15] += w3.w * hj;
  }

  // out[o] = sum_{k,c} acc[k][c] * Wf[(k*64+c)*O + o]  (c = lane)
  float part[O];
#pragma unroll
  for (int o = 0; o < O; o++) part[o] = 0.f;
#pragma unroll
  for (int k = 0; k < KDIM; k++) {
    const float* Wr = Wf + (size_t)(k * WIDTH + lane) * O;
#pragma unroll
    for (int o = 0; o < O; o++) part[o] += acc[k] * Wr[o];
  }
#pragma unroll
  for (int o = 0; o < O; o++) {
    float s = part[o];
    for (int m = 32; m > 0; m >>= 1) s += __shfl_xor(s, m, 64);
    if (lane == o) cat[(size_t)n * WIDTH + coloff + o] = s;
  }
}

// -------- out = lrelu(bn(cat)) @ outW + identity; store per dtype flag ------
__global__ __launch_bounds__(256) void final_kernel(
    const float* __restrict__ cat, const float* __restrict__ mean,
    const float* __restrict__ var,
    const void* __restrict__ g, const void* __restrict__ b,
    const void* __restrict__ outW, const int* __restrict__ flagp,
    const float* __restrict__ identity, void* __restrict__ out) {
  int isf = *flagp;
  int i = blockIdx.x;
  int t = threadIdx.x;   // 256 = COUT
  __shared__ float cn[WIDTH];
  if (t < WIDTH) {
    float xn = (cat[(size_t)i * WIDTH + t] - mean[t]) * rsqrtf(var[t] + BN_EPS);
    cn[t] = lrelu(xn * ldf(g, t, isf) + ldf(b, t, isf), SLOPE);
  }
  __syncthreads();
  float s = identity[(size_t)i * COUT + t];
#pragma unroll
  for (int k = 0; k < WIDTH; k++) s += cn[k] * ldf(outW, (size_t)k * COUT + t, isf);
  size_t oidx = (size_t)i * COUT + t;
  if (isf) ((float*)out)[oidx] = s;
  else     ((__hip_bfloat16*)out)[oidx] = __float2bfloat16(s);
}

extern "C" void kernel_launch(void* const* d_in, const int* in_sizes, int n_in,
                              void* d_out, int out_size, void* d_ws, size_t ws_size,
                              hipStream_t stream) {
  const void* x    = d_in[0];
  const void* pos  = d_in[1];
  const void* ori  = d_in[2];
  const int* seq  = (const int*)d_in[3];
  // d_in[4] = batch (unused; edge lists already encode grouping)
  const int* src1 = (const int*)d_in[5];  const int* dst1 = (const int*)d_in[6];
  const int* src2 = (const int*)d_in[7];  const int* dst2 = (const int*)d_in[8];
  const int* src3 = (const int*)d_in[9];  const int* dst3 = (const int*)d_in[10];
  const void* id_g  = d_in[11]; const void* id_b  = d_in[12]; const void* id_W = d_in[13];
  const void* in_g  = d_in[14]; const void* in_b  = d_in[15]; const void* in_W = d_in[16];
  const void* mid_g = d_in[17]; const void* mid_b = d_in[18];
  const void* Ws1   = d_in[19]; const void* bs1   = d_in[20]; const void* W1   = d_in[21];
  const void* Ws2   = d_in[22]; const void* bs2   = d_in[23]; const void* W2   = d_in[24];
  const void* Ws3   = d_in[25]; const void* bs3   = d_in[26]; const void* W3   = d_in[27];
  const void* out_g = d_in[28]; const void* out_b = d_in[29]; const void* out_W = d_in[30];

  const int E1 = in_sizes[5], E2 = in_sizes[7], E3 = in_sizes[9];

  float* wsp = (float*)d_ws;
  size_t off = 0;
  auto alloc = [&](size_t n) { float* p = wsp + off; off += (n + 63) & ~(size_t)63; return p; };
  int*   flag  = (int*)alloc(64);
  float* meanx = alloc(CIN);   float* varx = alloc(CIN);
  float* meanh = alloc(WIDTH); float* varh = alloc(WIDTH);
  float* meanc = alloc(WIDTH); float* varc = alloc(WIDTH);
  float* A     = alloc((size_t)N_NODES * CIN);
  float* B     = alloc((size_t)N_NODES * CIN);
  float* ident = alloc((size_t)N_NODES * COUT);
  float* hpre  = alloc((size_t)N_NODES * WIDTH);
  float* hbuf  = alloc((size_t)N_NODES * WIDTH);
  float* catb  = alloc((size_t)N_NODES * WIDTH);
  float* Wf1   = alloc(1024 * 32);
  float* Wf2   = alloc(1024 * 16);
  float* Wf3   = alloc(1024 * 16);
  float* w1    = alloc((size_t)E1 * KDIM);
  float* w2    = alloc((size_t)E2 * KDIM);
  float* w3    = alloc((size_t)E3 * KDIM);
  (void)ws_size; (void)n_in; (void)out_size;

  // 0. dtype sniff (writes flag; everything downstream branches uniformly)
  sniff_kernel<<<1, 64, 0, stream>>>(x, flag);
  // 1. stats of x (shared by id/in BN)
  col_stats_in_kernel<<<CIN, 256, 0, stream>>>(x, N_NODES, CIN, flag, meanx, varx);
  // 2. A/B activations
  act_ab_kernel<<<(N_NODES * CIN) / 256, 256, 0, stream>>>(x, flag, meanx, varx, id_g, id_b, in_g, in_b, A, B);
  // 3. identity = A @ id_W ; h_pre = B @ in_W
  gemm_act_kernel<<<dim3(COUT / 64, N_NODES / 4), 256, 0, stream>>>(A, id_W, flag, ident, CIN, COUT);
  gemm_act_kernel<<<dim3(WIDTH / 64, N_NODES / 4), 256, 0, stream>>>(B, in_W, flag, hpre, CIN, WIDTH);
  // 4. mid BN stats + activation -> h
  col_stats_f32_kernel<<<WIDTH, 256, 0, stream>>>(hpre, N_NODES, WIDTH, meanh, varh);
  bnleaky_kernel<<<(N_NODES * WIDTH) / 256, 256, 0, stream>>>(hpre, meanh, varh, mid_g, mid_b, flag, hbuf, WIDTH - 1);
  // 5. branch GEMM weights -> f32
  cvt_kernel<<<(1024 * 32 + 255) / 256, 256, 0, stream>>>(W1, flag, Wf1, 1024 * 32);
  cvt_kernel<<<(1024 * 16 + 255) / 256, 256, 0, stream>>>(W2, flag, Wf2, 1024 * 16);
  cvt_kernel<<<(1024 * 16 + 255) / 256, 256, 0, stream>>>(W3, flag, Wf3, 1024 * 16);
  // 6. per-edge gate weights
  edge_w_kernel<<<(E1 + 255) / 256, 256, 0, stream>>>(src1, dst1, pos, ori, seq, Ws1, bs1, flag, w1, E1, 1.0f / 2.70f, 2);
  edge_w_kernel<<<(E2 + 255) / 256, 256, 0, stream>>>(src2, dst2, pos, ori, seq, Ws2, bs2, flag, w2, E2, 1.0f / 1.80f, 3);
  edge_w_kernel<<<(E3 + 255) / 256, 256, 0, stream>>>(src3, dst3, pos, ori, seq, Ws3, bs3, flag, w3, E3, 1.0f / 1.35f, 5);
  // 7. per-node aggregation + branch GEMM -> cat columns [0:32),[32:48),[48:64)
  agg_kernel<32><<<N_NODES / 4, 256, 0, stream>>>(src1, dst1, E1, hbuf, w1, Wf1, catb, 0);
  agg_kernel<16><<<N_NODES / 4, 256, 0, stream>>>(src2, dst2, E2, hbuf, w2, Wf2, catb, 32);
  agg_kernel<16><<<N_NODES / 4, 256, 0, stream>>>(src3, dst3, E3, hbuf, w3, Wf3, catb, 48);
  // 8. out BN stats + final GEMM + residual
  col_stats_f32_kernel<<<WIDTH, 256, 0, stream>>>(catb, N_NODES, WIDTH, meanc, varc);
  final_kernel<<<N_NODES, COUT, 0, stream>>>(catb, meanc, varc, out_g, out_b, out_W, flag, ident, d_out);
}

// Round 3
// 364.536 us; speedup vs baseline: 1.5797x; 1.5797x over previous
//
#include <hip/hip_runtime.h>
#include <hip/hip_bf16.h>

#define N_NODES 4096
#define CIN     128
#define COUT    256
#define WIDTH   64
#define KDIM    16
#define SLOPE   0.1f
#define WSLOPE  0.2f
#define BN_EPS  1e-5f

__device__ __forceinline__ float lrelu(float x, float s) { return x > 0.f ? x : s * x; }

// Load a "float input" element: the harness may store float32 (per reference)
// or bf16 (dataset conversion). `isf32` is a runtime-uniform flag.
__device__ __forceinline__ float ldf(const void* p, size_t i, int isf32) {
  return isf32 ? ((const float*)p)[i]
               : __bfloat162float(((const __hip_bfloat16*)p)[i]);
}

// ---- dtype sniff: reinterpret x as bf16; f32 data shows huge/NaN values ----
__global__ void sniff_kernel(const void* x, int* flag) {
  int t = threadIdx.x;
  const __hip_bfloat16* p = (const __hip_bfloat16*)x;
  int bad = 0;
  for (int i = t; i < 256; i += 64) {
    float v = __bfloat162float(p[i]);
    if (!(fabsf(v) < 1e4f)) bad = 1;   // catches huge and NaN
  }
  unsigned long long m = __ballot(bad);
  if (t == 0) *flag = (m != 0ull) ? 1 : 0;   // 1 => underlying data is f32
}

// ---------------- column mean / biased var over M rows (input array) --------
__global__ __launch_bounds__(256) void col_stats_in_kernel(
    const void* __restrict__ X, int M, int C, const int* __restrict__ flagp,
    float* __restrict__ mean, float* __restrict__ var) {
  int isf = *flagp;
  int c = blockIdx.x;
  int t = threadIdx.x;
  float s = 0.f, sq = 0.f;
  for (int r = t; r < M; r += 256) {
    float v = ldf(X, (size_t)r * C + c, isf);
    s += v; sq += v * v;
  }
  __shared__ float ls[256], lq[256];
  ls[t] = s; lq[t] = sq; __syncthreads();
  for (int st = 128; st > 0; st >>= 1) {
    if (t < st) { ls[t] += ls[t + st]; lq[t] += lq[t + st]; }
    __syncthreads();
  }
  if (t == 0) {
    float m = ls[0] / M;
    mean[c] = m;
    var[c] = lq[0] / M - m * m;
  }
}

// ---------------- same but over a f32 workspace array ----------------
__global__ __launch_bounds__(256) void col_stats_f32_kernel(
    const float* __restrict__ X, int M, int C,
    float* __restrict__ mean, float* __restrict__ var) {
  int c = blockIdx.x;
  int t = threadIdx.x;
  float s = 0.f, sq = 0.f;
  for (int r = t; r < M; r += 256) {
    float v = X[(size_t)r * C + c];
    s += v; sq += v * v;
  }
  __shared__ float ls[256], lq[256];
  ls[t] = s; lq[t] = sq; __syncthreads();
  for (int st = 128; st > 0; st >>= 1) {
    if (t < st) { ls[t] += ls[t + st]; lq[t] += lq[t + st]; }
    __syncthreads();
  }
  if (t == 0) {
    float m = ls[0] / M;
    mean[c] = m;
    var[c] = lq[0] / M - m * m;
  }
}

// -------- A = lrelu(bn_id(x)), B = lrelu(bn_in(x)) (shared x stats) --------
__global__ __launch_bounds__(256) void act_ab_kernel(
    const void* __restrict__ x, const int* __restrict__ flagp,
    const float* __restrict__ mean, const float* __restrict__ var,
    const void* __restrict__ gA, const void* __restrict__ bA,
    const void* __restrict__ gB, const void* __restrict__ bB,
    float* __restrict__ A, float* __restrict__ B) {
  int isf = *flagp;
  int idx = blockIdx.x * 256 + threadIdx.x;      // over N*CIN
  int c = idx & (CIN - 1);
  float xn = (ldf(x, idx, isf) - mean[c]) * rsqrtf(var[c] + BN_EPS);
  A[idx] = lrelu(xn * ldf(gA, c, isf) + ldf(bA, c, isf), SLOPE);
  B[idx] = lrelu(xn * ldf(gB, c, isf) + ldf(bB, c, isf), SLOPE);
}

// -------- C[M,Nd] = A[M,Kd] (f32 ws) @ W[Kd,Nd] (input); wave per row --------
__global__ __launch_bounds__(256) void gemm_act_kernel(
    const float* __restrict__ A, const void* __restrict__ W,
    const int* __restrict__ flagp, float* __restrict__ C, int Kd, int Nd) {
  int isf = *flagp;
  int lane = threadIdx.x & 63;
  int wv = threadIdx.x >> 6;
  int j = blockIdx.x * 64 + lane;
  int i = blockIdx.y * 4 + wv;
  const float* Ar = A + (size_t)i * Kd;
  float s = 0.f;
  for (int k = 0; k < Kd; k += 4) {
    float4 a = *(const float4*)(Ar + k);
    s += a.x * ldf(W, (size_t)(k + 0) * Nd + j, isf);
    s += a.y * ldf(W, (size_t)(k + 1) * Nd + j, isf);
    s += a.z * ldf(W, (size_t)(k + 2) * Nd + j, isf);
    s += a.w * ldf(W, (size_t)(k + 3) * Nd + j, isf);
  }
  C[(size_t)i * Nd + j] = s;
}

// -------- Y = lrelu(bn(X)) elementwise on ws f32, C channels pow2 --------
__global__ __launch_bounds__(256) void bnleaky_kernel(
    const float* __restrict__ X, const float* __restrict__ mean,
    const float* __restrict__ var,
    const void* __restrict__ g, const void* __restrict__ b,
    const int* __restrict__ flagp, float* __restrict__ Y, int Cmask) {
  int isf = *flagp;
  int idx = blockIdx.x * 256 + threadIdx.x;
  int c = idx & Cmask;
  float xn = (X[idx] - mean[c]) * rsqrtf(var[c] + BN_EPS);
  Y[idx] = lrelu(xn * ldf(g, c, isf) + ldf(b, c, isf), SLOPE);
}

// -------- input -> f32 convert --------
__global__ __launch_bounds__(256) void cvt_kernel(
    const void* __restrict__ src, const int* __restrict__ flagp,
    float* __restrict__ dst, int n) {
  int isf = *flagp;
  int i = blockIdx.x * 256 + threadIdx.x;
  if (i < n) dst[i] = ldf(src, i, isf);
}

// -------- per-edge gate weights w[E,16] --------
__global__ __launch_bounds__(256) void edge_w_kernel(
    const int* __restrict__ src, const int* __restrict__ dst,
    const void* __restrict__ pos, const void* __restrict__ ori,
    const int* __restrict__ seq,
    const void* __restrict__ Ws, const void* __restrict__ bs,
    const int* __restrict__ flagp,
    float* __restrict__ wbuf, int E, float inv_r, int hl) {
  int isf = *flagp;
  int e = blockIdx.x * 256 + threadIdx.x;
  if (e >= E) return;
  int j = src[e], i = dst[e];
  float px = ldf(pos, j * 3 + 0, isf) - ldf(pos, i * 3 + 0, isf);
  float py = ldf(pos, j * 3 + 1, isf) - ldf(pos, i * 3 + 1, isf);
  float pz = ldf(pos, j * 3 + 2, isf) - ldf(pos, i * 3 + 2, isf);
  float dist = sqrtf(px * px + py * py + pz * pz);
  float inv = 1.0f / (dist + 1e-9f);
  float dx = px * inv, dy = py * inv, dz = pz * inv;
  float fi[9], fj[9];
#pragma unroll
  for (int t = 0; t < 9; t++) {
    fi[t] = ldf(ori, (size_t)i * 9 + t, isf);
    fj[t] = ldf(ori, (size_t)j * 9 + t, isf);
  }
  float feat[7];
  feat[0] = dist * inv_r;
  feat[1] = fi[0] * dx + fi[1] * dy + fi[2] * dz;
  feat[2] = fi[3] * dx + fi[4] * dy + fi[5] * dz;
  feat[3] = fi[6] * dx + fi[7] * dy + fi[8] * dz;
  feat[4] = fi[0] * fj[0] + fi[1] * fj[1] + fi[2] * fj[2];
  feat[5] = fi[3] * fj[3] + fi[4] * fj[4] + fi[5] * fj[5];
  feat[6] = fi[6] * fj[6] + fi[7] * fj[7] + fi[8] * fj[8];
  int d = seq[j] - seq[i];
  d = d < -hl ? -hl : (d > hl ? hl : d);
  int bin = d + hl;
  const size_t Wo = (size_t)bin * 7 * KDIM;
  const size_t bo = (size_t)bin * KDIM;
#pragma unroll
  for (int k = 0; k < KDIM; k++) {
    float a = ldf(bs, bo + k, isf);
#pragma unroll
    for (int c = 0; c < 7; c++) a += feat[c] * ldf(Ws, Wo + c * KDIM + k, isf);
    wbuf[(size_t)e * KDIM + k] = lrelu(a, WSLOPE);
  }
}

// -------- per-node aggregation + branch GEMM (dst sorted ascending) --------
// Register-lean epilogue: dump acc[16] (lane=channel c) to a per-wave LDS
// strip in (k*64+c) linear order (== Wf row order), then re-map lanes:
// o = lane % O, q = lane / O; each lane dots a 1024/Q chunk of agg against
// Wf[:,o], then shfl_xor reduce over q. No part[] array -> no spills.
template <int O>
__global__ __launch_bounds__(256) void agg_kernel(
    const int* __restrict__ src, const int* __restrict__ dst, int E,
    const float* __restrict__ h, const float* __restrict__ wbuf,
    const float* __restrict__ Wf, float* __restrict__ cat, int coloff) {
  constexpr int Q = 64 / O;              // lanes sharing one output column
  constexpr int CHUNK = (KDIM * WIDTH) / Q;
  __shared__ float lds[4][KDIM * WIDTH]; // 4 waves x 4 KB
  int lane = threadIdx.x & 63;
  int wv = threadIdx.x >> 6;
  int n = blockIdx.x * 4 + wv;           // wave per node

  int lo = 0, hi = E;
  while (lo < hi) { int mid = (lo + hi) >> 1; if (dst[mid] < n) lo = mid + 1; else hi = mid; }
  int start = lo;
  hi = E;
  while (lo < hi) { int mid = (lo + hi) >> 1; if (dst[mid] < n + 1) lo = mid + 1; else hi = mid; }
  int end = lo;

  float acc[KDIM];
#pragma unroll
  for (int k = 0; k < KDIM; k++) acc[k] = 0.f;

  for (int e = start; e < end; e++) {
    int j = src[e];
    float hj = h[(size_t)j * WIDTH + lane];
    const float4* wv4 = (const float4*)(wbuf + (size_t)e * KDIM);
    float4 w0 = wv4[0], w1 = wv4[1], w2 = wv4[2], w3 = wv4[3];
    acc[0]  += w0.x * hj; acc[1]  += w0.y * hj; acc[2]  += w0.z * hj; acc[3]  += w0.w * hj;
    acc[4]  += w1.x * hj; acc[5]  += w1.y * hj; acc[6]  += w1.z * hj; acc[7]  += w1.w * hj;
    acc[8]  += w2.x * hj; acc[9]  += w2.y * hj; acc[10] += w2.z * hj; acc[11] += w2.w * hj;
    acc[12] += w3.x * hj; acc[13] += w3.y * hj; acc[14] += w3.z * hj; acc[15] += w3.w * hj;
  }

#pragma unroll
  for (int k = 0; k < KDIM; k++) lds[wv][k * WIDTH + lane] = acc[k];
  __syncthreads();

  int o = lane % O;
  int q = lane / O;
  const float* base = lds[wv] + q * CHUNK;          // float4-aligned
  const float* wrow = Wf + (size_t)(q * CHUNK) * O + o;
  float part = 0.f;
#pragma unroll 4
  for (int i = 0; i < CHUNK; i += 4) {
    float4 a = *(const float4*)(base + i);
    part += a.x * wrow[(size_t)(i + 0) * O];
    part += a.y * wrow[(size_t)(i + 1) * O];
    part += a.z * wrow[(size_t)(i + 2) * O];
    part += a.w * wrow[(size_t)(i + 3) * O];
  }
#pragma unroll
  for (int m = O; m < 64; m <<= 1) part += __shfl_xor(part, m, 64);
  if (lane < O) cat[(size_t)n * WIDTH + coloff + lane] = part;
}

// -------- out = lrelu(bn(cat)) @ outW + identity; store per dtype flag ------
__global__ __launch_bounds__(256) void final_kernel(
    const float* __restrict__ cat, const float* __restrict__ mean,
    const float* __restrict__ var,
    const void* __restrict__ g, const void* __restrict__ b,
    const void* __restrict__ outW, const int* __restrict__ flagp,
    const float* __restrict__ identity, void* __restrict__ out) {
  int isf = *flagp;
  int i = blockIdx.x;
  int t = threadIdx.x;   // 256 = COUT
  __shared__ float cn[WIDTH];
  if (t < WIDTH) {
    float xn = (cat[(size_t)i * WIDTH + t] - mean[t]) * rsqrtf(var[t] + BN_EPS);
    cn[t] = lrelu(xn * ldf(g, t, isf) + ldf(b, t, isf), SLOPE);
  }
  __syncthreads();
  float s = identity[(size_t)i * COUT + t];
#pragma unroll
  for (int k = 0; k < WIDTH; k++) s += cn[k] * ldf(outW, (size_t)k * COUT + t, isf);
  size_t oidx = (size_t)i * COUT + t;
  if (isf) ((float*)out)[oidx] = s;
  else     ((__hip_bfloat16*)out)[oidx] = __float2bfloat16(s);
}

extern "C" void kernel_launch(void* const* d_in, const int* in_sizes, int n_in,
                              void* d_out, int out_size, void* d_ws, size_t ws_size,
                              hipStream_t stream) {
  const void* x    = d_in[0];
  const void* pos  = d_in[1];
  const void* ori  = d_in[2];
  const int* seq  = (const int*)d_in[3];
  // d_in[4] = batch (unused; edge lists already encode grouping)
  const int* src1 = (const int*)d_in[5];  const int* dst1 = (const int*)d_in[6];
  const int* src2 = (const int*)d_in[7];  const int* dst2 = (const int*)d_in[8];
  const int* src3 = (const int*)d_in[9];  const int* dst3 = (const int*)d_in[10];
  const void* id_g  = d_in[11]; const void* id_b  = d_in[12]; const void* id_W = d_in[13];
  const void* in_g  = d_in[14]; const void* in_b  = d_in[15]; const void* in_W = d_in[16];
  const void* mid_g = d_in[17]; const void* mid_b = d_in[18];
  const void* Ws1   = d_in[19]; const void* bs1   = d_in[20]; const void* W1   = d_in[21];
  const void* Ws2   = d_in[22]; const void* bs2   = d_in[23]; const void* W2   = d_in[24];
  const void* Ws3   = d_in[25]; const void* bs3   = d_in[26]; const void* W3   = d_in[27];
  const void* out_g = d_in[28]; const void* out_b = d_in[29]; const void* out_W = d_in[30];

  const int E1 = in_sizes[5], E2 = in_sizes[7], E3 = in_sizes[9];

  float* wsp = (float*)d_ws;
  size_t off = 0;
  auto alloc = [&](size_t n) { float* p = wsp + off; off += (n + 63) & ~(size_t)63; return p; };
  int*   flag  = (int*)alloc(64);
  float* meanx = alloc(CIN);   float* varx = alloc(CIN);
  float* meanh = alloc(WIDTH); float* varh = alloc(WIDTH);
  float* meanc = alloc(WIDTH); float* varc = alloc(WIDTH);
  float* A     = alloc((size_t)N_NODES * CIN);
  float* B     = alloc((size_t)N_NODES * CIN);
  float* ident = alloc((size_t)N_NODES * COUT);
  float* hpre  = alloc((size_t)N_NODES * WIDTH);
  float* hbuf  = alloc((size_t)N_NODES * WIDTH);
  float* catb  = alloc((size_t)N_NODES * WIDTH);
  float* Wf1   = alloc(1024 * 32);
  float* Wf2   = alloc(1024 * 16);
  float* Wf3   = alloc(1024 * 16);
  float* w1    = alloc((size_t)E1 * KDIM);
  float* w2    = alloc((size_t)E2 * KDIM);
  float* w3    = alloc((size_t)E3 * KDIM);
  (void)ws_size; (void)n_in; (void)out_size;

  // 0. dtype sniff (writes flag; everything downstream branches uniformly)
  sniff_kernel<<<1, 64, 0, stream>>>(x, flag);
  // 1. stats of x (shared by id/in BN)
  col_stats_in_kernel<<<CIN, 256, 0, stream>>>(x, N_NODES, CIN, flag, meanx, varx);
  // 2. A/B activations
  act_ab_kernel<<<(N_NODES * CIN) / 256, 256, 0, stream>>>(x, flag, meanx, varx, id_g, id_b, in_g, in_b, A, B);
  // 3. identity = A @ id_W ; h_pre = B @ in_W
  gemm_act_kernel<<<dim3(COUT / 64, N_NODES / 4), 256, 0, stream>>>(A, id_W, flag, ident, CIN, COUT);
  gemm_act_kernel<<<dim3(WIDTH / 64, N_NODES / 4), 256, 0, stream>>>(B, in_W, flag, hpre, CIN, WIDTH);
  // 4. mid BN stats + activation -> h
  col_stats_f32_kernel<<<WIDTH, 256, 0, stream>>>(hpre, N_NODES, WIDTH, meanh, varh);
  bnleaky_kernel<<<(N_NODES * WIDTH) / 256, 256, 0, stream>>>(hpre, meanh, varh, mid_g, mid_b, flag, hbuf, WIDTH - 1);
  // 5. branch GEMM weights -> f32
  cvt_kernel<<<(1024 * 32 + 255) / 256, 256, 0, stream>>>(W1, flag, Wf1, 1024 * 32);
  cvt_kernel<<<(1024 * 16 + 255) / 256, 256, 0, stream>>>(W2, flag, Wf2, 1024 * 16);
  cvt_kernel<<<(1024 * 16 + 255) / 256, 256, 0, stream>>>(W3, flag, Wf3, 1024 * 16);
  // 6. per-edge gate weights
  edge_w_kernel<<<(E1 + 255) / 256, 256, 0, stream>>>(src1, dst1, pos, ori, seq, Ws1, bs1, flag, w1, E1, 1.0f / 2.70f, 2);
  edge_w_kernel<<<(E2 + 255) / 256, 256, 0, stream>>>(src2, dst2, pos, ori, seq, Ws2, bs2, flag, w2, E2, 1.0f / 1.80f, 3);
  edge_w_kernel<<<(E3 + 255) / 256, 256, 0, stream>>>(src3, dst3, pos, ori, seq, Ws3, bs3, flag, w3, E3, 1.0f / 1.35f, 5);
  // 7. per-node aggregation + branch GEMM -> cat columns [0:32),[32:48),[48:64)
  agg_kernel<32><<<N_NODES / 4, 256, 0, stream>>>(src1, dst1, E1, hbuf, w1, Wf1, catb, 0);
  agg_kernel<16><<<N_NODES / 4, 256, 0, stream>>>(src2, dst2, E2, hbuf, w2, Wf2, catb, 32);
  agg_kernel<16><<<N_NODES / 4, 256, 0, stream>>>(src3, dst3, E3, hbuf, w3, Wf3, catb, 48);
  // 8. out BN stats + final GEMM + residual
  col_stats_f32_kernel<<<WIDTH, 256, 0, stream>>>(catb, N_NODES, WIDTH, meanc, varc);
  final_kernel<<<N_NODES, COUT, 0, stream>>>(catb, meanc, varc, out_g, out_b, out_W, flag, ident, d_out);
}

// Round 4
// 326.571 us; speedup vs baseline: 1.7634x; 1.1163x over previous
//
#include <hip/hip_runtime.h>
#include <hip/hip_bf16.h>

#define N_NODES 4096
#define CIN     128
#define COUT    256
#define WIDTH   64
#define KDIM    16
#define SLOPE   0.1f
#define WSLOPE  0.2f
#define BN_EPS  1e-5f

__device__ __forceinline__ float lrelu(float x, float s) { return x > 0.f ? x : s * x; }

// Load a "float input" element: f32 (per reference) or bf16; runtime flag.
__device__ __forceinline__ float ldf(const void* p, size_t i, int isf32) {
  return isf32 ? ((const float*)p)[i]
               : __bfloat162float(((const __hip_bfloat16*)p)[i]);
}

// ---- dtype sniff: reinterpret x as bf16; f32 data shows huge/NaN values ----
__global__ void sniff_kernel(const void* x, int* flag) {
  int t = threadIdx.x;
  const __hip_bfloat16* p = (const __hip_bfloat16*)x;
  int bad = 0;
  for (int i = t; i < 256; i += 64) {
    float v = __bfloat162float(p[i]);
    if (!(fabsf(v) < 1e4f)) bad = 1;
  }
  unsigned long long m = __ballot(bad);
  if (t == 0) *flag = (m != 0ull) ? 1 : 0;   // 1 => underlying data is f32
}

// ---------------- column mean / biased var over M rows (input array) --------
__global__ __launch_bounds__(256) void col_stats_in_kernel(
    const void* __restrict__ X, int M, int C, const int* __restrict__ flagp,
    float* __restrict__ mean, float* __restrict__ var) {
  int isf = *flagp;
  int c = blockIdx.x;
  int t = threadIdx.x;
  float s = 0.f, sq = 0.f;
  for (int r = t; r < M; r += 256) {
    float v = ldf(X, (size_t)r * C + c, isf);
    s += v; sq += v * v;
  }
  __shared__ float ls[256], lq[256];
  ls[t] = s; lq[t] = sq; __syncthreads();
  for (int st = 128; st > 0; st >>= 1) {
    if (t < st) { ls[t] += ls[t + st]; lq[t] += lq[t + st]; }
    __syncthreads();
  }
  if (t == 0) {
    float m = ls[0] / M;
    mean[c] = m;
    var[c] = lq[0] / M - m * m;
  }
}

// ---------------- same but over a f32 workspace array ----------------
__global__ __launch_bounds__(256) void col_stats_f32_kernel(
    const float* __restrict__ X, int M, int C,
    float* __restrict__ mean, float* __restrict__ var) {
  int c = blockIdx.x;
  int t = threadIdx.x;
  float s = 0.f, sq = 0.f;
  for (int r = t; r < M; r += 256) {
    float v = X[(size_t)r * C + c];
    s += v; sq += v * v;
  }
  __shared__ float ls[256], lq[256];
  ls[t] = s; lq[t] = sq; __syncthreads();
  for (int st = 128; st > 0; st >>= 1) {
    if (t < st) { ls[t] += ls[t + st]; lq[t] += lq[t + st]; }
    __syncthreads();
  }
  if (t == 0) {
    float m = ls[0] / M;
    mean[c] = m;
    var[c] = lq[0] / M - m * m;
  }
}

// -------- A = lrelu(bn_id(x)), B = lrelu(bn_in(x)) (shared x stats) --------
__global__ __launch_bounds__(256) void act_ab_kernel(
    const void* __restrict__ x, const int* __restrict__ flagp,
    const float* __restrict__ mean, const float* __restrict__ var,
    const void* __restrict__ gA, const void* __restrict__ bA,
    const void* __restrict__ gB, const void* __restrict__ bB,
    float* __restrict__ A, float* __restrict__ B) {
  int isf = *flagp;
  int idx = blockIdx.x * 256 + threadIdx.x;      // over N*CIN
  int c = idx & (CIN - 1);
  float xn = (ldf(x, idx, isf) - mean[c]) * rsqrtf(var[c] + BN_EPS);
  A[idx] = lrelu(xn * ldf(gA, c, isf) + ldf(bA, c, isf), SLOPE);
  B[idx] = lrelu(xn * ldf(gB, c, isf) + ldf(bB, c, isf), SLOPE);
}

// -------- C[M,Nd] = A[M,Kd] (f32 ws) @ W[Kd,Nd] (input); wave per row --------
__global__ __launch_bounds__(256) void gemm_act_kernel(
    const float* __restrict__ A, const void* __restrict__ W,
    const int* __restrict__ flagp, float* __restrict__ C, int Kd, int Nd) {
  int isf = *flagp;
  int lane = threadIdx.x & 63;
  int wv = threadIdx.x >> 6;
  int j = blockIdx.x * 64 + lane;
  int i = blockIdx.y * 4 + wv;
  const float* Ar = A + (size_t)i * Kd;
  float s = 0.f;
  for (int k = 0; k < Kd; k += 4) {
    float4 a = *(const float4*)(Ar + k);
    s += a.x * ldf(W, (size_t)(k + 0) * Nd + j, isf);
    s += a.y * ldf(W, (size_t)(k + 1) * Nd + j, isf);
    s += a.z * ldf(W, (size_t)(k + 2) * Nd + j, isf);
    s += a.w * ldf(W, (size_t)(k + 3) * Nd + j, isf);
  }
  C[(size_t)i * Nd + j] = s;
}

// -------- Y = lrelu(bn(X)) elementwise on ws f32, C channels pow2 --------
__global__ __launch_bounds__(256) void bnleaky_kernel(
    const float* __restrict__ X, const float* __restrict__ mean,
    const float* __restrict__ var,
    const void* __restrict__ g, const void* __restrict__ b,
    const int* __restrict__ flagp, float* __restrict__ Y, int Cmask) {
  int isf = *flagp;
  int idx = blockIdx.x * 256 + threadIdx.x;
  int c = idx & Cmask;
  float xn = (X[idx] - mean[c]) * rsqrtf(var[c] + BN_EPS);
  Y[idx] = lrelu(xn * ldf(g, c, isf) + ldf(b, c, isf), SLOPE);
}

// -------- fused convert of the 3 branch weight matrices -> f32 ws --------
__global__ __launch_bounds__(256) void cvt3_kernel(
    const void* __restrict__ W1, const void* __restrict__ W2,
    const void* __restrict__ W3, const int* __restrict__ flagp,
    float* __restrict__ dst) {   // dst = Wf1|Wf2|Wf3 contiguous (32K|16K|16K)
  int isf = *flagp;
  int i = blockIdx.x * 256 + threadIdx.x;   // 0..65535
  float v;
  if (i < 32768)      v = ldf(W1, i, isf);
  else if (i < 49152) v = ldf(W2, i - 32768, isf);
  else                v = ldf(W3, i - 49152, isf);
  dst[i] = v;
}

// -------- rowptr[b][n] = lower_bound(dst_b, n); rowptr[b][N] = E_b --------
__global__ __launch_bounds__(256) void rowptr_kernel(
    const int* __restrict__ d1, int E1, const int* __restrict__ d2, int E2,
    const int* __restrict__ d3, int E3, int* __restrict__ rp) {
  int t = blockIdx.x * 256 + threadIdx.x;   // 3 * (N+1)
  if (t >= 3 * (N_NODES + 1)) return;
  int b = t / (N_NODES + 1);
  int n = t % (N_NODES + 1);
  const int* d = (b == 0) ? d1 : (b == 1) ? d2 : d3;
  int E = (b == 0) ? E1 : (b == 1) ? E2 : E3;
  int lo = 0, hi = E;
  if (n >= N_NODES) lo = E;
  else {
    while (lo < hi) { int mid = (lo + hi) >> 1; if (d[mid] < n) lo = mid + 1; else hi = mid; }
  }
  rp[(size_t)b * (N_NODES + 1) + n] = lo;
}

// -------- fused per-edge gate weights for all 3 branches --------
struct EdgeParams {
  const int* src; const int* dst;
  const void* Ws; const void* bs;
  float* wbuf; int E; float inv_r; int hl;
};

__global__ __launch_bounds__(256) void edge_w3_kernel(
    EdgeParams p0, EdgeParams p1, EdgeParams p2,
    const void* __restrict__ pos, const void* __restrict__ ori,
    const int* __restrict__ seq, const int* __restrict__ flagp) {
  int b = blockIdx.y;
  EdgeParams p = (b == 0) ? p0 : (b == 1) ? p1 : p2;
  int isf = *flagp;
  int e = blockIdx.x * 256 + threadIdx.x;
  if (e >= p.E) return;
  int j = p.src[e], i = p.dst[e];
  float px = ldf(pos, j * 3 + 0, isf) - ldf(pos, i * 3 + 0, isf);
  float py = ldf(pos, j * 3 + 1, isf) - ldf(pos, i * 3 + 1, isf);
  float pz = ldf(pos, j * 3 + 2, isf) - ldf(pos, i * 3 + 2, isf);
  float dist = sqrtf(px * px + py * py + pz * pz);
  float inv = 1.0f / (dist + 1e-9f);
  float dx = px * inv, dy = py * inv, dz = pz * inv;
  float fi[9], fj[9];
#pragma unroll
  for (int t = 0; t < 9; t++) {
    fi[t] = ldf(ori, (size_t)i * 9 + t, isf);
    fj[t] = ldf(ori, (size_t)j * 9 + t, isf);
  }
  float feat[7];
  feat[0] = dist * p.inv_r;
  feat[1] = fi[0] * dx + fi[1] * dy + fi[2] * dz;
  feat[2] = fi[3] * dx + fi[4] * dy + fi[5] * dz;
  feat[3] = fi[6] * dx + fi[7] * dy + fi[8] * dz;
  feat[4] = fi[0] * fj[0] + fi[1] * fj[1] + fi[2] * fj[2];
  feat[5] = fi[3] * fj[3] + fi[4] * fj[4] + fi[5] * fj[5];
  feat[6] = fi[6] * fj[6] + fi[7] * fj[7] + fi[8] * fj[8];
  int d = seq[j] - seq[i];
  d = d < -p.hl ? -p.hl : (d > p.hl ? p.hl : d);
  int bin = d + p.hl;
  const size_t Wo = (size_t)bin * 7 * KDIM;
  const size_t bo = (size_t)bin * KDIM;
#pragma unroll
  for (int k = 0; k < KDIM; k++) {
    float a = ldf(p.bs, bo + k, isf);
#pragma unroll
    for (int c = 0; c < 7; c++) a += feat[c] * ldf(p.Ws, Wo + c * KDIM + k, isf);
    p.wbuf[(size_t)e * KDIM + k] = lrelu(a, WSLOPE);
  }
}

// -------- fused per-node aggregation + branch GEMM, all 3 branches --------
// Block per (node, branch); 4 waves split the edge range (stride 4);
// LDS combine; 256-thread epilogue GEMM vs Wf; LDS cross-wave reduce.
struct AggParams {
  const int* src; const float* wbuf; const float* Wf;
  int O; int coloff;
};

__global__ __launch_bounds__(256) void agg3_kernel(
    AggParams p0, AggParams p1, AggParams p2,
    const int* __restrict__ rowptr,
    const float* __restrict__ h, float* __restrict__ cat) {
  int b = blockIdx.y;
  AggParams p = (b == 0) ? p0 : (b == 1) ? p1 : p2;
  int n = blockIdx.x;
  int t = threadIdx.x;
  int lane = t & 63;
  int wv = t >> 6;

  const int* rp = rowptr + (size_t)b * (N_NODES + 1);
  int start = rp[n], end = rp[n + 1];

  float acc[KDIM];
#pragma unroll
  for (int k = 0; k < KDIM; k++) acc[k] = 0.f;

  int e = start + wv;
  int jn = (e < end) ? p.src[e] : 0;
  for (; e < end; e += 4) {
    int j = jn;
    int en = e + 4;
    if (en < end) jn = p.src[en];            // prefetch next gather index
    float hj = h[(size_t)j * WIDTH + lane];
    const float4* w4 = (const float4*)(p.wbuf + (size_t)e * KDIM);
    float4 w0 = w4[0], w1 = w4[1], w2 = w4[2], w3 = w4[3];
    acc[0]  += w0.x * hj; acc[1]  += w0.y * hj; acc[2]  += w0.z * hj; acc[3]  += w0.w * hj;
    acc[4]  += w1.x * hj; acc[5]  += w1.y * hj; acc[6]  += w1.z * hj; acc[7]  += w1.w * hj;
    acc[8]  += w2.x * hj; acc[9]  += w2.y * hj; acc[10] += w2.z * hj; acc[11] += w2.w * hj;
    acc[12] += w3.x * hj; acc[13] += w3.y * hj; acc[14] += w3.z * hj; acc[15] += w3.w * hj;
  }

  __shared__ float lds[4][KDIM * WIDTH];   // 16 KB
  __shared__ float pw[4][WIDTH];           // 1 KB
#pragma unroll
  for (int k = 0; k < KDIM; k++) lds[wv][k * WIDTH + lane] = acc[k];
  __syncthreads();

  // sum the 4 wave strips into strip 0 (disjoint index partition per thread)
  for (int i = t; i < KDIM * WIDTH; i += 256) {
    lds[0][i] = lds[0][i] + lds[1][i] + lds[2][i] + lds[3][i];
  }
  __syncthreads();

  // epilogue: out[o] = sum_i agg[i] * Wf[i*O + o], split across 256 threads
  int O = p.O;
  int o = t & (O - 1);
  int q = t / O;                 // 0..Q-1, Q = 256/O
  int chunk = (KDIM * WIDTH * O) >> 8;     // 1024/Q
  const float* base = lds[0] + q * chunk;
  const float* wrow = p.Wf + (size_t)(q * chunk) * O + o;
  float part = 0.f;
  for (int i = 0; i < chunk; i += 4) {
    float4 a = *(const float4*)(base + i);
    part += a.x * wrow[(size_t)(i + 0) * O];
    part += a.y * wrow[(size_t)(i + 1) * O];
    part += a.z * wrow[(size_t)(i + 2) * O];
    part += a.w * wrow[(size_t)(i + 3) * O];
  }
  for (int m = O; m < 64; m <<= 1) part += __shfl_xor(part, m, 64);
  if (lane < O) pw[wv][lane] = part;       // lane==o holds wave partial
  __syncthreads();
  if (t < O) {
    cat[(size_t)n * WIDTH + p.coloff + t] = pw[0][t] + pw[1][t] + pw[2][t] + pw[3][t];
  }
}

// -------- out = lrelu(bn(cat)) @ outW + identity; store per dtype flag ------
__global__ __launch_bounds__(256) void final_kernel(
    const float* __restrict__ cat, const float* __restrict__ mean,
    const float* __restrict__ var,
    const void* __restrict__ g, const void* __restrict__ b,
    const void* __restrict__ outW, const int* __restrict__ flagp,
    const float* __restrict__ identity, void* __restrict__ out) {
  int isf = *flagp;
  int i = blockIdx.x;
  int t = threadIdx.x;   // 256 = COUT
  __shared__ float cn[WIDTH];
  if (t < WIDTH) {
    float xn = (cat[(size_t)i * WIDTH + t] - mean[t]) * rsqrtf(var[t] + BN_EPS);
    cn[t] = lrelu(xn * ldf(g, t, isf) + ldf(b, t, isf), SLOPE);
  }
  __syncthreads();
  float s = identity[(size_t)i * COUT + t];
#pragma unroll
  for (int k = 0; k < WIDTH; k++) s += cn[k] * ldf(outW, (size_t)k * COUT + t, isf);
  size_t oidx = (size_t)i * COUT + t;
  if (isf) ((float*)out)[oidx] = s;
  else     ((__hip_bfloat16*)out)[oidx] = __float2bfloat16(s);
}

extern "C" void kernel_launch(void* const* d_in, const int* in_sizes, int n_in,
                              void* d_out, int out_size, void* d_ws, size_t ws_size,
                              hipStream_t stream) {
  const void* x    = d_in[0];
  const void* pos  = d_in[1];
  const void* ori  = d_in[2];
  const int* seq  = (const int*)d_in[3];
  const int* src1 = (const int*)d_in[5];  const int* dst1 = (const int*)d_in[6];
  const int* src2 = (const int*)d_in[7];  const int* dst2 = (const int*)d_in[8];
  const int* src3 = (const int*)d_in[9];  const int* dst3 = (const int*)d_in[10];
  const void* id_g  = d_in[11]; const void* id_b  = d_in[12]; const void* id_W = d_in[13];
  const void* in_g  = d_in[14]; const void* in_b  = d_in[15]; const void* in_W = d_in[16];
  const void* mid_g = d_in[17]; const void* mid_b = d_in[18];
  const void* Ws1   = d_in[19]; const void* bs1   = d_in[20]; const void* W1   = d_in[21];
  const void* Ws2   = d_in[22]; const void* bs2   = d_in[23]; const void* W2   = d_in[24];
  const void* Ws3   = d_in[25]; const void* bs3   = d_in[26]; const void* W3   = d_in[27];
  const void* out_g = d_in[28]; const void* out_b = d_in[29]; const void* out_W = d_in[30];

  const int E1 = in_sizes[5], E2 = in_sizes[7], E3 = in_sizes[9];

  float* wsp = (float*)d_ws;
  size_t off = 0;
  auto alloc = [&](size_t n) { float* p = wsp + off; off += (n + 63) & ~(size_t)63; return p; };
  int*   flag  = (int*)alloc(64);
  float* meanx = alloc(CIN);   float* varx = alloc(CIN);
  float* meanh = alloc(WIDTH); float* varh = alloc(WIDTH);
  float* meanc = alloc(WIDTH); float* varc = alloc(WIDTH);
  float* A     = alloc((size_t)N_NODES * CIN);
  float* B     = alloc((size_t)N_NODES * CIN);
  float* ident = alloc((size_t)N_NODES * COUT);
  float* hpre  = alloc((size_t)N_NODES * WIDTH);
  float* hbuf  = alloc((size_t)N_NODES * WIDTH);
  float* catb  = alloc((size_t)N_NODES * WIDTH);
  float* Wf1   = alloc(1024 * 32);        // contiguous: Wf1|Wf2|Wf3
  float* Wf2   = alloc(1024 * 16);
  float* Wf3   = alloc(1024 * 16);
  int*   rowp  = (int*)alloc(3 * (N_NODES + 1));
  float* w1    = alloc((size_t)E1 * KDIM);
  float* w2    = alloc((size_t)E2 * KDIM);
  float* w3    = alloc((size_t)E3 * KDIM);
  (void)ws_size; (void)n_in; (void)out_size;

  // 0. dtype sniff
  sniff_kernel<<<1, 64, 0, stream>>>(x, flag);
  // 1. stats of x (shared by id/in BN)
  col_stats_in_kernel<<<CIN, 256, 0, stream>>>(x, N_NODES, CIN, flag, meanx, varx);
  // 2. A/B activations
  act_ab_kernel<<<(N_NODES * CIN) / 256, 256, 0, stream>>>(x, flag, meanx, varx, id_g, id_b, in_g, in_b, A, B);
  // 3. identity = A @ id_W ; h_pre = B @ in_W
  gemm_act_kernel<<<dim3(COUT / 64, N_NODES / 4), 256, 0, stream>>>(A, id_W, flag, ident, CIN, COUT);
  gemm_act_kernel<<<dim3(WIDTH / 64, N_NODES / 4), 256, 0, stream>>>(B, in_W, flag, hpre, CIN, WIDTH);
  // 4. mid BN stats + activation -> h
  col_stats_f32_kernel<<<WIDTH, 256, 0, stream>>>(hpre, N_NODES, WIDTH, meanh, varh);
  bnleaky_kernel<<<(N_NODES * WIDTH) / 256, 256, 0, stream>>>(hpre, meanh, varh, mid_g, mid_b, flag, hbuf, WIDTH - 1);
  // 5. branch GEMM weights -> f32 (fused), rowptr (fused)
  cvt3_kernel<<<65536 / 256, 256, 0, stream>>>(W1, W2, W3, flag, Wf1);
  rowptr_kernel<<<(3 * (N_NODES + 1) + 255) / 256, 256, 0, stream>>>(dst1, E1, dst2, E2, dst3, E3, rowp);
  // 6. per-edge gate weights (fused over branches)
  EdgeParams ep0{src1, dst1, Ws1, bs1, w1, E1, 1.0f / 2.70f, 2};
  EdgeParams ep1{src2, dst2, Ws2, bs2, w2, E2, 1.0f / 1.80f, 3};
  EdgeParams ep2{src3, dst3, Ws3, bs3, w3, E3, 1.0f / 1.35f, 5};
  int maxE = E1 > E2 ? (E1 > E3 ? E1 : E3) : (E2 > E3 ? E2 : E3);
  edge_w3_kernel<<<dim3((maxE + 255) / 256, 3), 256, 0, stream>>>(ep0, ep1, ep2, pos, ori, seq, flag);
  // 7. fused per-node aggregation + branch GEMMs -> cat
  AggParams ap0{src1, w1, Wf1, 32, 0};
  AggParams ap1{src2, w2, Wf2, 16, 32};
  AggParams ap2{src3, w3, Wf3, 16, 48};
  agg3_kernel<<<dim3(N_NODES, 3), 256, 0, stream>>>(ap0, ap1, ap2, rowp, hbuf, catb);
  // 8. out BN stats + final GEMM + residual
  col_stats_f32_kernel<<<WIDTH, 256, 0, stream>>>(catb, N_NODES, WIDTH, meanc, varc);
  final_kernel<<<N_NODES, COUT, 0, stream>>>(catb, meanc, varc, out_g, out_b, out_W, flag, ident, d_out);
}